// Round 2
// baseline (220.457 us; speedup 1.0000x reference)
//
#include <hip/hip_runtime.h>

// Problem: S=8192, K=1024, O=4096
// out_q[s,o] = clip(round(int8dot(x[s,:], w[o,:]) * sx*sw/sy[s]), -128, 127)
// d_out = [ out_q as float (S*O) | scale_y (S) ]
//
// R7 == R6 resubmitted (R6 bench died at container level, no kernel signal).
// GEMM K-loop: 3-slot LDS ring, 2-deep prefetch, counted waits:
//   s_waitcnt vmcnt(4) lgkmcnt(0) ; s_barrier ; issue stage(t+2) ; compute(t)
// The newest 4 global_load_lds stay in flight across every barrier (T4,
// "never drain vmcnt to 0 in the main loop"). Data layout, pack kernel,
// fragment reads and epilogue are byte-identical to the verified R5 kernel.

#define S_DIM 8192
#define K_DIM 1024
#define O_DIM 4096
#define BM 128
#define BN 128
#define BK 64
#define NITER (K_DIM / BK)
#define TILE_BYTES (BM * BK)  // 8192 B staging tile

using i32x4 = __attribute__((ext_vector_type(4))) int;

__device__ __forceinline__ void load_lds16(const void* g, void* l) {
  __builtin_amdgcn_global_load_lds(
      (const __attribute__((address_space(1))) void*)g,
      (__attribute__((address_space(3))) void*)l, 16, 0, 0);
}

// ---------------- pack: int32 -> int8 into STAGING-TILE layout ----------------
// Output layout (A): tile t = band*16 + ktile (band = s/128, ktile = k/64),
// 8 KB each. Within tile: byte r*64 + cs*16 holds chunk (cs ^ (r&3)) of row
// band*128+r  (bank-swizzle baked in, identical LDS image to R5's stager).
// One thread per 16 B output chunk: reads 16 int32 (64 B), writes uint4.
__global__ void pack_kernel(const int* __restrict__ xi, const int* __restrict__ wi,
                            const float* __restrict__ sy,
                            uint4* __restrict__ ap, uint4* __restrict__ bp,
                            float* __restrict__ out_sy) {
  const int tid = blockIdx.x * blockDim.x + threadIdx.x;
  const int nA = S_DIM * K_DIM / 16;  // 512K chunks
  const int nB = O_DIM * K_DIM / 16;  // 256K chunks

  const int* src;
  uint4* dst;
  int j;
  if (tid < nA) {
    src = xi; dst = ap; j = tid;
  } else if (tid < nA + nB) {
    src = wi; dst = bp; j = tid - nA;
  } else {
    return;
  }
  const int t = j >> 9;          // tile index (512 chunks/tile)
  const int idx = j & 511;
  const int r = idx >> 2;        // row within tile 0..127
  const int cs = idx & 3;        // chunk slot
  const int c = cs ^ (r & 3);    // global chunk (swizzle)
  const int band = t >> 4;       // 16 ktiles per band
  const int kt = t & 15;
  const int row = band * 128 + r;
  const int4* s4 = (const int4*)src + row * 256 + kt * 16 + c * 4;
  int4 v0 = s4[0], v1 = s4[1], v2 = s4[2], v3 = s4[3];
  uint4 o;
  o.x = (v0.x & 0xff) | ((v0.y & 0xff) << 8) | ((v0.z & 0xff) << 16) | (((unsigned)v0.w & 0xff) << 24);
  o.y = (v1.x & 0xff) | ((v1.y & 0xff) << 8) | ((v1.z & 0xff) << 16) | (((unsigned)v1.w & 0xff) << 24);
  o.z = (v2.x & 0xff) | ((v2.y & 0xff) << 8) | ((v2.z & 0xff) << 16) | (((unsigned)v2.w & 0xff) << 24);
  o.w = (v3.x & 0xff) | ((v3.y & 0xff) << 8) | ((v3.z & 0xff) << 16) | (((unsigned)v3.w & 0xff) << 24);
  dst[j] = o;
  if (tid < S_DIM) out_sy[tid] = sy[tid];
}

// ---------------- int8 MFMA GEMM, ring-3 counted-vmcnt staging ----------------
// Block: 256 threads = 4 waves in 2x2; wave owns 64x64 = 4x4 grid of
// 16x16x64 i8 MFMA tiles. 3-slot LDS ring (3 x 16 KB), 2-deep prefetch,
// ONE raw s_barrier per K-step, vmcnt never drained to 0 until the tail.
// Correctness of the single barrier:
//  - readiness of slot t: each wave drains its OWN stage(t) loads
//    (vmcnt(4): stage(t+1)'s 4 loads stay in flight) BEFORE the barrier,
//    so after the barrier all 16 staging loads for slot t have landed.
//  - overwrite of slot (t+2)%3 == slot(t-1): stage(t+2) is issued only
//    AFTER the barrier; every wave drained lgkmcnt(0) before the barrier,
//    so no wave still has an in-flight ds_read of slot(t-1).
__global__ __launch_bounds__(256, 3) void gemm_i8_kernel(
    const signed char* __restrict__ Ap,  // tiled-packed x
    const signed char* __restrict__ Bp,  // tiled-packed w
    const float* __restrict__ sx, const float* __restrict__ sw,
    const float* __restrict__ sy, float* __restrict__ out) {
  __shared__ __align__(16) signed char As[3][TILE_BYTES];
  __shared__ __align__(16) signed char Bs[3][TILE_BYTES];

  const int tid = threadIdx.x;
  const int wave = tid >> 6;
  const int lane = tid & 63;
  const int wm = wave >> 1;  // 0..1: wave row in block
  const int wn = wave & 1;   // 0..1: wave col in block
  const int rowBase = blockIdx.x * BM;   // x-fast over S keeps B L2-resident
  const int colBase = blockIdx.y * BN;

  const int soff = wave * 1024 + lane * 16;  // same offset in tile and LDS
  const signed char* gA = Ap + (size_t)blockIdx.x * NITER * TILE_BYTES + soff;
  const signed char* gB = Bp + (size_t)blockIdx.y * NITER * TILE_BYTES + soff;
  signed char* ldsA = (signed char*)As + wave * 1024;  // + slot*8192 below
  signed char* ldsB = (signed char*)Bs + wave * 1024;

  i32x4 acc[4][4] = {};

  const int fr = lane & 15;                            // fragment row
  const int fq = (((lane >> 4) ^ (fr & 3)) & 3) * 16;  // swizzled chunk slot

  // Prologue: stage tiles 0 and 1 into ring slots 0 and 1. Two ORDERED
  // groups of 4 loads each (counted vmcnt depends on issue order, so pin
  // the group boundary with a memory-clobber scheduling fence).
  load_lds16(gA, ldsA);
  load_lds16(gA + 4096, ldsA + 4096);
  load_lds16(gB, ldsB);
  load_lds16(gB + 4096, ldsB + 4096);
  asm volatile("" ::: "memory");
  load_lds16(gA + TILE_BYTES, ldsA + TILE_BYTES);
  load_lds16(gA + TILE_BYTES + 4096, ldsA + TILE_BYTES + 4096);
  load_lds16(gB + TILE_BYTES, ldsB + TILE_BYTES);
  load_lds16(gB + TILE_BYTES + 4096, ldsB + TILE_BYTES + 4096);

#pragma unroll
  for (int it = 0; it < NITER; ++it) {
    // Outstanding per wave here: stage(it) [oldest 4] + stage(it+1) [newest 4].
    // Wait for own stage(it) only; drain LDS reads of iter it-1 (race guard
    // for the post-barrier overwrite of slot (it+2)%3 == slot (it-1)%3).
    if (it + 1 < NITER) {
      asm volatile("s_waitcnt vmcnt(4) lgkmcnt(0)" ::: "memory");
    } else {
      asm volatile("s_waitcnt vmcnt(0) lgkmcnt(0)" ::: "memory");
    }
    __builtin_amdgcn_s_barrier();
    asm volatile("" ::: "memory");  // no memory op crosses the barrier

    if (it + 2 < NITER) {  // 2-deep prefetch into ring slot (it+2)%3
      const int boff = ((it + 2) % 3) * TILE_BYTES;
      const size_t goff = (size_t)(it + 2) * TILE_BYTES;
      load_lds16(gA + goff, ldsA + boff);
      load_lds16(gA + goff + 4096, ldsA + boff + 4096);
      load_lds16(gB + goff, ldsB + boff);
      load_lds16(gB + goff + 4096, ldsB + boff + 4096);
    }

    const signed char* curA = As[it % 3];
    const signed char* curB = Bs[it % 3];
    i32x4 bf[4];
#pragma unroll
    for (int ni = 0; ni < 4; ++ni)
      bf[ni] = *(const i32x4*)(curB + (wn * 64 + ni * 16 + fr) * BK + fq);

#pragma unroll
    for (int mi = 0; mi < 4; ++mi) {
      i32x4 af = *(const i32x4*)(curA + (wm * 64 + mi * 16 + fr) * BK + fq);
#pragma unroll
      for (int ni = 0; ni < 4; ++ni)
        acc[mi][ni] =
            __builtin_amdgcn_mfma_i32_16x16x64_i8(af, bf[ni], acc[mi][ni], 0, 0, 0);
    }
  }

  // Epilogue. C/D layout: col = lane&15, row = (lane>>4)*4 + reg.
  const float sxw = sx[0] * sw[0];
  const int quad = lane >> 4;
#pragma unroll
  for (int mi = 0; mi < 4; ++mi) {
#pragma unroll
    for (int r = 0; r < 4; ++r) {
      const int s = rowBase + wm * 64 + mi * 16 + quad * 4 + r;
      const float rs = sxw / sy[s];
      float* orow = out + (size_t)s * O_DIM + colBase + wn * 64 + fr;
#pragma unroll
      for (int ni = 0; ni < 4; ++ni) {
        float f = rintf((float)acc[mi][ni][r] * rs);
        f = fminf(127.0f, fmaxf(-128.0f, f));
        orow[ni * 16] = f;
      }
    }
  }
}

extern "C" void kernel_launch(void* const* d_in, const int* in_sizes, int n_in,
                              void* d_out, int out_size, void* d_ws, size_t ws_size,
                              hipStream_t stream) {
  const int* x = (const int*)d_in[0];        // [S,K] int8 values as int32
  const int* w = (const int*)d_in[1];        // [O,K] int8 values as int32
  const float* sx = (const float*)d_in[2];
  const float* sw = (const float*)d_in[3];
  const float* sy = (const float*)d_in[4];   // [S]
  float* out = (float*)d_out;

  uint4* ap = (uint4*)d_ws;                                   // 8 MB tiled A
  uint4* bp = ap + (size_t)S_DIM * K_DIM / 16;                // 4 MB tiled B

  const int total = S_DIM * K_DIM / 16 + O_DIM * K_DIM / 16;  // 768K threads
  pack_kernel<<<(total + 255) / 256, 256, 0, stream>>>(
      x, w, sy, ap, bp, out + (size_t)S_DIM * O_DIM);

  dim3 grid(S_DIM / BM, O_DIM / BN);  // (64, 32), row tiles fast
  gemm_i8_kernel<<<grid, 256, 0, stream>>>(
      (const signed char*)ap, (const signed char*)bp, sx, sw, sy, out);
}

// Round 3
// 199.561 us; speedup vs baseline: 1.1047x; 1.1047x over previous
//
#include <hip/hip_runtime.h>

// Problem: S=8192, K=1024, O=4096
// out_q[s,o] = clip(round(int8dot(x[s,:], w[o,:]) * sx*sw/sy[s]), -128, 127)
// d_out = [ out_q as float (S*O) | scale_y (S) ]
//
// R8: post-mortem of R7's regression (220.5 vs R5's 200.7): ring-3 at
// BM=BN=128 cost 4->3 blocks/CU (16->12 waves/CU); occupancy loss beat the
// prefetch gain. R8 keeps ring-3 + counted vmcnt but restores 16 waves/CU:
//   BM=256, BN=128, 512 threads (8 waves, 4Mx2N), LDS 3x24KB=72KB -> 2 blk/CU.
// Per-wave work per K-step identical to R5 (64x64 out, 16 MFMA, 8 ds_read).
// B staging traffic halves (384->256 MB). Pack layout byte-identical to R5.

#define S_DIM 8192
#define K_DIM 1024
#define O_DIM 4096
#define BM 256
#define BN 128
#define BK 64
#define NITER (K_DIM / BK)
#define TILE_BYTES (128 * BK)   // 8192 B band-tile (pack layout unit)
#define A_SLOT (2 * TILE_BYTES) // 16 KB: two band-tiles stacked
#define B_SLOT TILE_BYTES       // 8 KB

using i32x4 = __attribute__((ext_vector_type(4))) int;

__device__ __forceinline__ void load_lds16(const void* g, void* l) {
  __builtin_amdgcn_global_load_lds(
      (const __attribute__((address_space(1))) void*)g,
      (__attribute__((address_space(3))) void*)l, 16, 0, 0);
}

// ---------------- pack: int32 -> int8 into STAGING-TILE layout ----------------
// (byte-identical to the verified R5 pack)
// Layout: tile t = band*16 + ktile (band = row/128, ktile = k/64), 8 KB each.
// Within tile: byte r*64 + cs*16 holds chunk (cs ^ (r&3)) of row band*128+r.
__global__ void pack_kernel(const int* __restrict__ xi, const int* __restrict__ wi,
                            const float* __restrict__ sy,
                            uint4* __restrict__ ap, uint4* __restrict__ bp,
                            float* __restrict__ out_sy) {
  const int tid = blockIdx.x * blockDim.x + threadIdx.x;
  const int nA = S_DIM * K_DIM / 16;  // 512K chunks
  const int nB = O_DIM * K_DIM / 16;  // 256K chunks

  const int* src;
  uint4* dst;
  int j;
  if (tid < nA) {
    src = xi; dst = ap; j = tid;
  } else if (tid < nA + nB) {
    src = wi; dst = bp; j = tid - nA;
  } else {
    return;
  }
  const int t = j >> 9;          // tile index (512 chunks/tile)
  const int idx = j & 511;
  const int r = idx >> 2;        // row within tile 0..127
  const int cs = idx & 3;        // chunk slot
  const int c = cs ^ (r & 3);    // global chunk (swizzle)
  const int band = t >> 4;       // 16 ktiles per band
  const int kt = t & 15;
  const int row = band * 128 + r;
  const int4* s4 = (const int4*)src + row * 256 + kt * 16 + c * 4;
  int4 v0 = s4[0], v1 = s4[1], v2 = s4[2], v3 = s4[3];
  uint4 o;
  o.x = (v0.x & 0xff) | ((v0.y & 0xff) << 8) | ((v0.z & 0xff) << 16) | (((unsigned)v0.w & 0xff) << 24);
  o.y = (v1.x & 0xff) | ((v1.y & 0xff) << 8) | ((v1.z & 0xff) << 16) | (((unsigned)v1.w & 0xff) << 24);
  o.z = (v2.x & 0xff) | ((v2.y & 0xff) << 8) | ((v2.z & 0xff) << 16) | (((unsigned)v2.w & 0xff) << 24);
  o.w = (v3.x & 0xff) | ((v3.y & 0xff) << 8) | ((v3.z & 0xff) << 16) | (((unsigned)v3.w & 0xff) << 24);
  dst[j] = o;
  if (tid < S_DIM) out_sy[tid] = sy[tid];
}

// ---------------- int8 MFMA GEMM, 256x128 tile, ring-3, 16 waves/CU ----------
// 512 threads = 8 waves in 4x2; wave owns 64x64 = 4x4 grid of 16x16x64 tiles.
// 3-slot LDS ring (72 KB), 2-deep prefetch, counted waits:
//   s_waitcnt vmcnt(3) lgkmcnt(0) ; s_barrier ; issue stage(t+2) ; compute(t)
// 3 global_load_lds calls per stage (A-half0, A-half1, B); each call moves
// 8 KB block-wide (8 waves x 1 KB). Steady-state in flight per wave:
// {stage(t):3, stage(t+1):3} -> vmcnt(3) drains own stage(t) only.
// Slot lifetime: stage(t+2) overwrites slot(t-1); issued only after the
// barrier that every wave reached with lgkmcnt(0) drained (no live ds_read).
__global__ __launch_bounds__(512, 4) void gemm_i8_kernel(
    const signed char* __restrict__ Ap,  // tiled-packed x
    const signed char* __restrict__ Bp,  // tiled-packed w
    const float* __restrict__ sx, const float* __restrict__ sw,
    const float* __restrict__ sy, float* __restrict__ out) {
  __shared__ __align__(16) signed char As[3][A_SLOT];  // 48 KB
  __shared__ __align__(16) signed char Bs[3][B_SLOT];  // 24 KB

  const int tid = threadIdx.x;
  const int wave = tid >> 6;
  const int lane = tid & 63;
  const int wm = wave >> 1;  // 0..3: wave row in block
  const int wn = wave & 1;   // 0..1: wave col in block
  const int rowBase = blockIdx.x * BM;   // x-fast over S keeps B L2-resident
  const int colBase = blockIdx.y * BN;

  const int soff = wave * 1024 + lane * 16;  // 8 waves cover 8 KB per call
  const signed char* gA0 = Ap + (size_t)(2 * blockIdx.x) * NITER * TILE_BYTES + soff;
  const signed char* gA1 = Ap + (size_t)(2 * blockIdx.x + 1) * NITER * TILE_BYTES + soff;
  const signed char* gB  = Bp + (size_t)blockIdx.y * NITER * TILE_BYTES + soff;
  signed char* ldsA = (signed char*)As + soff;  // + slot*A_SLOT (+TILE for half1)
  signed char* ldsB = (signed char*)Bs + soff;  // + slot*B_SLOT

  i32x4 acc[4][4] = {};

  const int fr = lane & 15;                            // fragment row
  const int fq = (((lane >> 4) ^ (fr & 3)) & 3) * 16;  // swizzled chunk slot

  // Prologue: stage K-tiles 0 and 1 into ring slots 0 and 1 (ordered groups).
  load_lds16(gA0, ldsA);
  load_lds16(gA1, ldsA + TILE_BYTES);
  load_lds16(gB, ldsB);
  asm volatile("" ::: "memory");
  {
    const size_t goff = TILE_BYTES;
    load_lds16(gA0 + goff, ldsA + A_SLOT);
    load_lds16(gA1 + goff, ldsA + A_SLOT + TILE_BYTES);
    load_lds16(gB + goff, ldsB + B_SLOT);
  }

#pragma unroll
  for (int it = 0; it < NITER; ++it) {
    // Drain own stage(it) (oldest 3); keep stage(it+1)'s 3 in flight.
    // lgkmcnt(0): no live ds_read of slot(it-1) before its overwrite below.
    if (it + 1 < NITER) {
      asm volatile("s_waitcnt vmcnt(3) lgkmcnt(0)" ::: "memory");
    } else {
      asm volatile("s_waitcnt vmcnt(0) lgkmcnt(0)" ::: "memory");
    }
    __builtin_amdgcn_s_barrier();
    asm volatile("" ::: "memory");  // no memory op crosses the barrier

    if (it + 2 < NITER) {  // 2-deep prefetch into ring slot (it+2)%3
      const int slot = (it + 2) % 3;
      const size_t goff = (size_t)(it + 2) * TILE_BYTES;
      load_lds16(gA0 + goff, ldsA + slot * A_SLOT);
      load_lds16(gA1 + goff, ldsA + slot * A_SLOT + TILE_BYTES);
      load_lds16(gB + goff, ldsB + slot * B_SLOT);
    }

    const signed char* curA = As[it % 3];
    const signed char* curB = Bs[it % 3];
    i32x4 bf[4];
#pragma unroll
    for (int ni = 0; ni < 4; ++ni)
      bf[ni] = *(const i32x4*)(curB + (wn * 64 + ni * 16 + fr) * BK + fq);

#pragma unroll
    for (int mi = 0; mi < 4; ++mi) {
      i32x4 af = *(const i32x4*)(curA + (wm * 64 + mi * 16 + fr) * BK + fq);
#pragma unroll
      for (int ni = 0; ni < 4; ++ni)
        acc[mi][ni] =
            __builtin_amdgcn_mfma_i32_16x16x64_i8(af, bf[ni], acc[mi][ni], 0, 0, 0);
    }
  }

  // Epilogue. C/D layout: col = lane&15, row = (lane>>4)*4 + reg.
  const float sxw = sx[0] * sw[0];
  const int quad = lane >> 4;
#pragma unroll
  for (int mi = 0; mi < 4; ++mi) {
#pragma unroll
    for (int r = 0; r < 4; ++r) {
      const int s = rowBase + wm * 64 + mi * 16 + quad * 4 + r;
      const float rs = sxw / sy[s];
      float* orow = out + (size_t)s * O_DIM + colBase + wn * 64 + fr;
#pragma unroll
      for (int ni = 0; ni < 4; ++ni) {
        float f = rintf((float)acc[mi][ni][r] * rs);
        f = fminf(127.0f, fmaxf(-128.0f, f));
        orow[ni * 16] = f;
      }
    }
  }
}

extern "C" void kernel_launch(void* const* d_in, const int* in_sizes, int n_in,
                              void* d_out, int out_size, void* d_ws, size_t ws_size,
                              hipStream_t stream) {
  const int* x = (const int*)d_in[0];        // [S,K] int8 values as int32
  const int* w = (const int*)d_in[1];        // [O,K] int8 values as int32
  const float* sx = (const float*)d_in[2];
  const float* sw = (const float*)d_in[3];
  const float* sy = (const float*)d_in[4];   // [S]
  float* out = (float*)d_out;

  uint4* ap = (uint4*)d_ws;                                   // 8 MB tiled A
  uint4* bp = ap + (size_t)S_DIM * K_DIM / 16;                // 4 MB tiled B

  const int total = S_DIM * K_DIM / 16 + O_DIM * K_DIM / 16;  // 768K threads
  pack_kernel<<<(total + 255) / 256, 256, 0, stream>>>(
      x, w, sy, ap, bp, out + (size_t)S_DIM * O_DIM);

  dim3 grid(S_DIM / BM, O_DIM / BN);  // (32, 32)
  gemm_i8_kernel<<<grid, 512, 0, stream>>>(
      (const signed char*)ap, (const signed char*)bp, sx, sw, sy, out);
}